// Round 15
// baseline (97.210 us; speedup 1.0000x reference)
//
#include <hip/hip_runtime.h>

// Problem constants (from reference)
#define B_ 32
#define C_ 32
#define T_ 8192
#define N_ 256
#define P_ 6
#define TV_ (T_ - P_ + 1)   // valid conv length = 8187
#define REP 40              // k_chars measurement replicas (y=0 stores; y>0 live-compute)

// =============================================================================
// MEASUREMENT ROUND on the r13 structure (61.5us best): k_chars gets a
// replica dim (blockIdx.y) so the dispatch exceeds the 150-166us poison fills
// and surfaces in the PMC top-5 with counters. (dur - 61.5)/39 = marginal
// steady-state k_chars cost; counters say WHY it costs 26us one-shot.
// =============================================================================

// ---------------------------------------------------------------------------
// Kernel 1 (r5 body + replica dim): decode one-hot -> chars[B][T] (u8 in u32).
// ---------------------------------------------------------------------------
__global__ void k_chars(const float* __restrict__ inp, unsigned* __restrict__ chars32) {
    int bx = blockIdx.x;                  // [0, B * T/1024)
    int z  = blockIdx.y;                  // replica; only z==0 stores
    int b  = bx >> 3;                     // T/1024 = 8 chunks per batch
    int t  = ((bx & 7) << 10) + (threadIdx.x << 2);
    const float* base = inp + (size_t)b * C_ * T_ + t;
    float ax = 0.f, ay = 0.f, az = 0.f, aw = 0.f;
    #pragma unroll
    for (int c = 0; c < C_; ++c) {
        float4 v = *(const float4*)(base + (size_t)c * T_);
        float fc = (float)c;
        ax += fc * v.x; ay += fc * v.y; az += fc * v.z; aw += fc * v.w;
    }
    unsigned w = ((unsigned)(ax + 0.5f))
               | ((unsigned)(ay + 0.5f) << 8)
               | ((unsigned)(az + 0.5f) << 16)
               | ((unsigned)(aw + 0.5f) << 24);
    if (z == 0) {
        chars32[((size_t)b * T_ + t) >> 2] = w;
    } else {
        asm volatile("" : : "v"(w));      // keep load+decode chain live (rule #17)
    }
}

// ---------------------------------------------------------------------------
// Kernel 2 (verbatim r13): r5 k_final + in-block tab derivation from `pat`.
// ---------------------------------------------------------------------------
__global__ void k_final(const unsigned char* __restrict__ chars,
                        const float* __restrict__ pat,
                        float* __restrict__ out) {
    __shared__ unsigned s32[258];         // 1024 chars + 8 halo bytes
    __shared__ unsigned s_tabs[32 * 12];  // this block's 32-n tab slice
    int tc  = blockIdx.x;                 // 0..7
    int ng  = blockIdx.y;                 // 0..7  (group of 32 n)
    int b   = blockIdx.z;                 // 0..31
    int tid = threadIdx.x;
    int t0  = tc << 10;
    int tb  = t0 + (tid << 2);
    int n0  = ng << 5;

    // ---- stage chars chunk ----
    const unsigned* csrc = (const unsigned*)(chars + (size_t)b * T_ + t0);
    s32[tid] = csrc[tid];
    if (tid < 2) {
        unsigned v = 0u;
        int gt = t0 + 1024 + tid * 4;     // byte index into chars[b][*]
        if (gt < T_) v = csrc[256 + tid];
        s32[256 + tid] = v;
    }

    // ---- derive this block's 32-n x 6-p tab slice ----
    if (tid < 192) {
        int nl = tid & 31;                // n_local
        int p  = tid >> 5;                // 0..5
        int n  = n0 + nl;
        float maxv = -3.402823466e+38f;
        float sum = 0.0f;
        unsigned mask = 0u;
        #pragma unroll
        for (int c = 0; c < C_; ++c) {
            float v = pat[((size_t)c * P_ + p) * N_ + n];
            sum += v;
            if (v > maxv) { maxv = v; mask = (1u << c); }
            else if (v == maxv) { mask |= (1u << c); }
        }
        if (!(sum > 0.0f)) mask = 0u;
        int pc = __popc(mask);
        unsigned req = (unsigned)(__ffs((int)mask) - 1);
        s_tabs[nl * 12 + p]     = (pc == 1) ? req * 0x01010101u : 0x7F7F7F7Fu;
        s_tabs[nl * 12 + 6 + p] = (pc == 0) ? 0u : 0x80808080u;
    }
    __syncthreads();

    // ---- match loop (verbatim r5), tabs from LDS ----
    unsigned w0 = s32[tid], w1 = s32[tid + 1], w2 = s32[tid + 2];
    unsigned cw0 = w0;
    unsigned cw1 = __builtin_amdgcn_alignbyte(w1, w0, 1);
    unsigned cw2 = __builtin_amdgcn_alignbyte(w1, w0, 2);
    unsigned cw3 = __builtin_amdgcn_alignbyte(w1, w0, 3);
    unsigned cw4 = w1;
    unsigned cw5 = __builtin_amdgcn_alignbyte(w2, w1, 1);

    const uint4* tp = (const uint4*)s_tabs;
    float* obase = out + ((size_t)(b * N_ + n0)) * T_ + tb;
    bool tail = (tc == 7) && (tb + 3 >= TV_);

    #pragma unroll 4
    for (int g = 0; g < 32; ++g) {
        uint4 A  = tp[g * 3 + 0];         // xs0..xs3  (uniform -> broadcast)
        uint4 Bv = tp[g * 3 + 1];         // xs4, xs5, om0, om1
        uint4 Cv = tp[g * 3 + 2];         // om2..om5

        unsigned orv;
        orv  = ((cw0 ^ A.x)  + 0x7F7F7F7FU) & Bv.z;
        orv |= ((cw1 ^ A.y)  + 0x7F7F7F7FU) & Bv.w;   // v_and_or_b32
        orv |= ((cw2 ^ A.z)  + 0x7F7F7F7FU) & Cv.x;
        orv |= ((cw3 ^ A.w)  + 0x7F7F7F7FU) & Cv.y;
        orv |= ((cw4 ^ Bv.x) + 0x7F7F7F7FU) & Cv.z;
        orv |= ((cw5 ^ Bv.y) + 0x7F7F7F7FU) & Cv.w;

        float res[4];
        #pragma unroll
        for (int j = 0; j < 4; ++j)
            res[j] = (orv & (0x80u << (8 * j))) ? 0.0f : 1.0f;

        if (tail) {                       // only last chunk's tail lanes
            unsigned act = Bv.z | Bv.w | Cv.x | Cv.y | Cv.z | Cv.w;
            float padf = (act == 0u) ? 1.0f : 0.0f;  // psum==0: pad matches
            #pragma unroll
            for (int j = 0; j < 4; ++j)
                if (tb + j >= TV_) res[j] = padf;
        }

        float4 r; r.x = res[0]; r.y = res[1]; r.z = res[2]; r.w = res[3];
        *(float4*)(obase + (size_t)g * T_) = r;
    }
}

// ---------------------------------------------------------------------------
extern "C" void kernel_launch(void* const* d_in, const int* in_sizes, int n_in,
                              void* d_out, int out_size, void* d_ws, size_t ws_size,
                              hipStream_t stream) {
    const float* input_   = (const float*)d_in[0];   // (B,C,T,1) one-hot fp32
    const float* patterns = (const float*)d_in[1];   // (C,P,1,N) fp32
    float* out = (float*)d_out;                      // (B,N,T,1) fp32

    // ws layout: [16384, 16384+256K) chars u8
    unsigned char* chars = (unsigned char*)d_ws + 16384;

    hipLaunchKernelGGL(k_chars, dim3(B_ * (T_ / 1024), REP), dim3(256), 0, stream,
                       input_, (unsigned*)chars);
    hipLaunchKernelGGL(k_final, dim3(T_ / 1024, N_ / 32, B_), dim3(256), 0, stream,
                       chars, patterns, out);
}